// Round 8
// baseline (203.229 us; speedup 1.0000x reference)
//
#include <hip/hip_runtime.h>

#define NN 100000
#define NE 600000
#define DD 128
#define NB 196      // src buckets: node >> 9  (99999>>9 = 195)
#define CHUNK 75000 // NE / 8 XCD-chunks
#define BPC 1172    // blocks per chunk = ceil(CHUNK/64)

typedef _Float16 half4_t __attribute__((ext_vector_type(4)));
typedef _Float16 half8_t __attribute__((ext_vector_type(8)));
typedef float f32x4 __attribute__((ext_vector_type(4)));

// XOR-swizzle for [row][256B] f16 LDS tiles (G4). Byte address; flips bits
// 4-6 only, so 8B/16B alignment within a 16B slot is preserved.
__device__ __forceinline__ int swzb(int row, int byte) {
  return row * 256 + (byte ^ ((row & 7) << 4));
}

__device__ __forceinline__ half8_t relu_add(half8_t a, half8_t b) {
  half8_t r;
#pragma unroll
  for (int j = 0; j < 8; ++j) {
    const _Float16 s = a[j] + b[j];
    r[j] = s > (_Float16)0 ? s : (_Float16)0;
  }
  return r;
}

// ---------------------------------------------------------------------------
// zero histogram (must precede prep's atomics; harness doesn't re-zero ws)
// ---------------------------------------------------------------------------
__global__ void zero_kernel(int* __restrict__ hist) {
  if (threadIdx.x < NB) hist[threadIdx.x] = 0;
}

// ---------------------------------------------------------------------------
// Prep kernel.
// Blocks [0,40): pack 5 weight matrices (128x128 f32, row-major [k][n]) into
// f16 fragment order (validated rounds 2-7):
//   packed[m][(nf*4+ks)*64 + l][j] = W[8*(l>>4)+32*ks+j][16*nf+(l&15)]
//   m: 0=W_src 1=W_tgt 2=W_proj[:128] 3=W_proj[128:] 4=W_mlp
// Blocks [40,552): decode edge_index into int32 idx[2*NE] (src then tgt) and
// histogram src>>9 into hist[NB]. int64-vs-int32 width detected per block.
// ---------------------------------------------------------------------------
__global__ void prep_kernel(const float* __restrict__ Wsrc,
                            const float* __restrict__ Wtgt,
                            const float* __restrict__ Wproj,
                            const float* __restrict__ Wmlp,
                            const unsigned int* __restrict__ eraw,
                            int* __restrict__ idx,
                            int* __restrict__ hist,
                            _Float16* __restrict__ packed) {
  const int bid = (int)blockIdx.x;
  const int tid = (int)threadIdx.x;
  if (bid < 40) {
    const int t = bid * 256 + tid;
    if (t >= 5 * 2048) return;
    const int m = t >> 11;
    const int rem = t & 2047;
    const int nf = rem >> 8;
    const int ks = (rem >> 6) & 3;
    const int l = rem & 63;
    const float* W;
    if (m == 0) W = Wsrc;
    else if (m == 1) W = Wtgt;
    else if (m == 2) W = Wproj;
    else if (m == 3) W = Wproj + 128 * DD;
    else W = Wmlp;
    const int col = (l & 15) + 16 * nf;
    const int k0 = 8 * (l >> 4) + 32 * ks;
    half8_t v;
#pragma unroll
    for (int j = 0; j < 8; ++j)
      v[j] = (_Float16)W[(size_t)(k0 + j) * DD + col];
    *reinterpret_cast<half8_t*>(packed + (size_t)m * 16384 +
                                (size_t)rem * 8) = v;
  } else {
    __shared__ int s_is64;
    __shared__ int lh[NB];
    if (tid < NB) lh[tid] = 0;
    if (tid < 64) {
      const unsigned long long b = __ballot(eraw[2 * tid + 1] != 0u);
      if (tid == 0) s_is64 = (b == 0ull) ? 1 : 0;
    }
    __syncthreads();
    const int is64 = s_is64;
    const size_t stride = (size_t)512 * 256;
    for (size_t i = (size_t)(bid - 40) * 256 + tid; i < 2 * (size_t)NE;
         i += stride) {
      const int v = (int)(is64 ? eraw[2 * i] : eraw[i]);
      idx[i] = v;
      if (i < (size_t)NE) atomicAdd(&lh[v >> 9], 1);
    }
    __syncthreads();
    if (tid < NB && lh[tid]) atomicAdd(&hist[tid], lh[tid]);
  }
}

// ---------------------------------------------------------------------------
// Exclusive scan of hist -> cursor (196 values; single thread is fine).
// ---------------------------------------------------------------------------
__global__ void scan_kernel(const int* __restrict__ hist,
                            int* __restrict__ cursor) {
  if (threadIdx.x == 0 && blockIdx.x == 0) {
    int acc = 0;
#pragma unroll 1
    for (int b = 0; b < NB; ++b) {
      cursor[b] = acc;
      acc += hist[b];
    }
  }
}

// ---------------------------------------------------------------------------
// Scatter edges into bucket order: sortedS/T/E[pos]. 1024 edges per block.
// Two LDS-atomic passes: count -> reserve global range -> rank -> write.
// Within-bucket order is nondeterministic; per-edge output is independent,
// so the final d_out is deterministic.
// ---------------------------------------------------------------------------
__global__ __launch_bounds__(256)
void scatter_kernel(const int* __restrict__ idx, int* __restrict__ cursor,
                    int* __restrict__ sortedS, int* __restrict__ sortedT,
                    int* __restrict__ sortedE) {
  __shared__ int lh[NB];
  __shared__ int lbase[NB];
  const int tid = (int)threadIdx.x;
  const int e0 = (int)blockIdx.x * 1024;
  if (tid < NB) lh[tid] = 0;
  __syncthreads();

  int sv[4], tv[4], bv[4];
  bool val[4];
#pragma unroll
  for (int k = 0; k < 4; ++k) {
    const int e = e0 + tid + k * 256;
    val[k] = e < NE;
    if (val[k]) {
      sv[k] = idx[e];
      tv[k] = idx[(size_t)NE + e];
      bv[k] = sv[k] >> 9;
      atomicAdd(&lh[bv[k]], 1);
    }
  }
  __syncthreads();
  if (tid < NB) {
    const int c = lh[tid];
    lbase[tid] = c ? atomicAdd(&cursor[tid], c) : 0;
  }
  __syncthreads();
  if (tid < NB) lh[tid] = 0;  // reuse as local rank counter
  __syncthreads();
#pragma unroll
  for (int k = 0; k < 4; ++k) {
    if (val[k]) {
      const int r = atomicAdd(&lh[bv[k]], 1);
      const int pos = lbase[bv[k]] + r;
      sortedS[pos] = sv[k];
      sortedT[pos] = tv[k];
      sortedE[pos] = e0 + tid + k * 256;
    }
  }
}

// ---------------------------------------------------------------------------
// Phase 1 (v2, unchanged from R6): per-node tables (f16 out).
//   A[n] = (sigmoid(x W_src) * x) @ W_proj[:128] + b_proj
//   B[n] = (sigmoid(x W_tgt) * x) @ W_proj[128:]
// 64 nodes/block, 4 waves; nf split across waves; W fragments in registers.
// ---------------------------------------------------------------------------
__global__ __launch_bounds__(256, 4)
void phase1_kernel(const float* __restrict__ Xg,
                   const _Float16* __restrict__ packW,
                   const float* __restrict__ bproj,
                   _Float16* __restrict__ Aout,
                   _Float16* __restrict__ Bout) {
  __shared__ _Float16 Xh[64 * DD];
  __shared__ _Float16 Th[64 * DD];
  const int tid = (int)threadIdx.x;
  const int row0 = (int)blockIdx.x * 64;
  const int rem = NN - row0;
  const int nvalid = rem < 64 ? rem : 64;

#pragma unroll
  for (int it = 0; it < 8; ++it) {
    const int i = tid + it * 256;
    const int r = i >> 5;
    const int c4 = i & 31;
    float4 v = make_float4(0.f, 0.f, 0.f, 0.f);
    if (r < nvalid)
      v = reinterpret_cast<const float4*>(Xg + (size_t)(row0 + r) * DD)[c4];
    half4_t h;
    h[0] = (_Float16)v.x; h[1] = (_Float16)v.y;
    h[2] = (_Float16)v.z; h[3] = (_Float16)v.w;
    *reinterpret_cast<half4_t*>(&Xh[swzb(r, c4 * 8) >> 1]) = h;
  }
  __syncthreads();

  const int l = tid & 63;
  const int w = tid >> 6;
  const int lr = l & 15;
  const int lg = l >> 4;

#pragma unroll 1
  for (int p = 0; p < 2; ++p) {
    const _Float16* __restrict__ wb1 = packW + (size_t)p * 16384 + l * 8;
    half8_t w1[2][4];
#pragma unroll
    for (int s = 0; s < 2; ++s)
#pragma unroll
      for (int ks = 0; ks < 4; ++ks)
        w1[s][ks] = *reinterpret_cast<const half8_t*>(
            wb1 + (size_t)(((2 * w + s) * 4 + ks)) * 512);

    f32x4 acc[4][2];
#pragma unroll
    for (int mf = 0; mf < 4; ++mf)
#pragma unroll
      for (int s = 0; s < 2; ++s) acc[mf][s] = (f32x4)0.f;
#pragma unroll
    for (int mf = 0; mf < 4; ++mf) {
      half8_t xf[4];
#pragma unroll
      for (int ks = 0; ks < 4; ++ks)
        xf[ks] = *reinterpret_cast<const half8_t*>(
            &Xh[swzb(mf * 16 + lr, lg * 16 + ks * 64) >> 1]);
#pragma unroll
      for (int ks = 0; ks < 4; ++ks)
#pragma unroll
        for (int s = 0; s < 2; ++s)
          acc[mf][s] = __builtin_amdgcn_mfma_f32_16x16x32_f16(
              w1[s][ks], xf[ks], acc[mf][s], 0, 0, 0);
    }

    if (p) __syncthreads();

#pragma unroll
    for (int mf = 0; mf < 4; ++mf)
#pragma unroll
      for (int s = 0; s < 2; ++s) {
        const int c0 = (2 * w + s) * 16 + lg * 4;
        const int node = mf * 16 + lr;
        const half4_t xh =
            *reinterpret_cast<const half4_t*>(&Xh[swzb(node, c0 * 2) >> 1]);
        half4_t th;
#pragma unroll
        for (int j = 0; j < 4; ++j) {
          const float t = (float)xh[j] / (1.f + __expf(-acc[mf][s][j]));
          th[j] = (_Float16)t;
        }
        *reinterpret_cast<half4_t*>(&Th[swzb(node, c0 * 2) >> 1]) = th;
      }
    __syncthreads();

    const _Float16* __restrict__ wb2 = packW + (size_t)(2 + p) * 16384 + l * 8;
    half8_t w2[2][4];
#pragma unroll
    for (int s = 0; s < 2; ++s)
#pragma unroll
      for (int ks = 0; ks < 4; ++ks)
        w2[s][ks] = *reinterpret_cast<const half8_t*>(
            wb2 + (size_t)(((2 * w + s) * 4 + ks)) * 512);

    f32x4 acc2[4][2];
#pragma unroll
    for (int mf = 0; mf < 4; ++mf)
#pragma unroll
      for (int s = 0; s < 2; ++s) acc2[mf][s] = (f32x4)0.f;
#pragma unroll
    for (int mf = 0; mf < 4; ++mf) {
      half8_t tf[4];
#pragma unroll
      for (int ks = 0; ks < 4; ++ks)
        tf[ks] = *reinterpret_cast<const half8_t*>(
            &Th[swzb(mf * 16 + lr, lg * 16 + ks * 64) >> 1]);
#pragma unroll
      for (int ks = 0; ks < 4; ++ks)
#pragma unroll
        for (int s = 0; s < 2; ++s)
          acc2[mf][s] = __builtin_amdgcn_mfma_f32_16x16x32_f16(
              w2[s][ks], tf[ks], acc2[mf][s], 0, 0, 0);
    }

    _Float16* __restrict__ dst = p ? Bout : Aout;
#pragma unroll
    for (int s = 0; s < 2; ++s) {
      const int c0 = (2 * w + s) * 16 + lg * 4;
      f32x4 bp = (f32x4)0.f;
      if (p == 0) bp = *reinterpret_cast<const f32x4*>(bproj + c0);
#pragma unroll
      for (int mf = 0; mf < 4; ++mf) {
        const int node = mf * 16 + lr;
        if (node < nvalid) {
          const f32x4 v = acc2[mf][s] + bp;
          half4_t h;
#pragma unroll
          for (int j = 0; j < 4; ++j) h[j] = (_Float16)v[j];
          *reinterpret_cast<half4_t*>(dst + (size_t)(row0 + node) * DD + c0) =
              h;
        }
      }
    }
  }
}

// ---------------------------------------------------------------------------
// Phase 2 (v4): out[e] = relu(A[src_e] + B[tgt_e]) @ W_mlp + b_mlp (f32 out)
// Consumes SORTED edges. Block bid handles sorted slice
//   (bid&7)*CHUNK + (bid>>3)*64
// so (with round-robin block->XCD dispatch) each XCD works one contiguous
// src-sorted chunk: A-row working set ~3.2 MB -> L2-resident; neighboring
// lanes share src rows -> request merging + L1 hits. B stays random.
// Output row address comes from sortedE (rows are 512B -> still coalesced).
// ---------------------------------------------------------------------------
__global__ __launch_bounds__(256, 5)
void phase2_kernel(const _Float16* __restrict__ At,
                   const _Float16* __restrict__ Bt,
                   const int* __restrict__ sortedS,
                   const int* __restrict__ sortedT,
                   const int* __restrict__ sortedE,
                   const _Float16* __restrict__ Wpk,
                   const float* __restrict__ bmlp,
                   float* __restrict__ out) {
  __shared__ _Float16 Wl[16384];  // 32 KB: full packed W_mlp
  const int tid = (int)threadIdx.x;
  const int l = tid & 63;
  const int w = tid >> 6;
  const int lr = l & 15;
  const int lg = l >> 4;
  const int bid = (int)blockIdx.x;
  const int base = (bid & 7) * CHUNK;
  const int loc = (bid >> 3) * 64 + w * 16 + lr;  // pos within chunk
  const bool valid = loc < CHUNK;
  const int g = base + (valid ? loc : 0);

  // dependent chain first: sorted records -> gather addresses -> gathers
  const int ia = sortedS[g];
  const int ib = sortedT[g];
  const int eo = sortedE[g];
  const _Float16* __restrict__ pa = At + (size_t)ia * DD + lg * 8;
  const _Float16* __restrict__ pb = Bt + (size_t)ib * DD + lg * 8;
  half8_t af[4], bf[4];
#pragma unroll
  for (int ks = 0; ks < 4; ++ks) {
    af[ks] = *reinterpret_cast<const half8_t*>(pa + ks * 32);
    bf[ks] = *reinterpret_cast<const half8_t*>(pb + ks * 32);
  }

  // stage W_mlp (overlaps the gathers in the same vmcnt window)
#pragma unroll
  for (int i = 0; i < 8; ++i) {
    const int c = tid + i * 256;
    reinterpret_cast<f32x4*>(Wl)[c] = reinterpret_cast<const f32x4*>(Wpk)[c];
  }

  f32x4 acc[8];
#pragma unroll
  for (int nf = 0; nf < 8; ++nf) acc[nf] = (f32x4)0.f;

  __syncthreads();  // drains vmcnt once: gathers + W loads all in flight

#pragma unroll
  for (int ks = 0; ks < 4; ++ks) {
    const half8_t r = relu_add(af[ks], bf[ks]);
#pragma unroll
    for (int nf = 0; nf < 8; ++nf) {
      const half8_t wf = *reinterpret_cast<const half8_t*>(
          &Wl[(size_t)(nf * 4 + ks) * 512 + l * 8]);
      acc[nf] =
          __builtin_amdgcn_mfma_f32_16x16x32_f16(wf, r, acc[nf], 0, 0, 0);
    }
  }

#pragma unroll
  for (int nf = 0; nf < 8; ++nf) {
    const int c0 = nf * 16 + lg * 4;
    const f32x4 bm = *reinterpret_cast<const f32x4*>(bmlp + c0);
    const f32x4 v = acc[nf] + bm;
    if (valid)
      __builtin_nontemporal_store(
          v, reinterpret_cast<f32x4*>(out + (size_t)eo * DD + c0));
  }
}

// ---------------------------------------------------------------------------
extern "C" void kernel_launch(void* const* d_in, const int* in_sizes, int n_in,
                              void* d_out, int out_size, void* d_ws,
                              size_t ws_size, hipStream_t stream) {
  (void)in_sizes; (void)n_in; (void)out_size; (void)ws_size;

  const float* X = (const float*)d_in[0];
  const unsigned int* eraw = (const unsigned int*)d_in[1];
  const float* Wsrc = (const float*)d_in[2];
  const float* Wtgt = (const float*)d_in[3];
  const float* Wproj = (const float*)d_in[4];
  const float* bproj = (const float*)d_in[5];
  const float* Wmlp = (const float*)d_in[6];
  const float* bmlp = (const float*)d_in[7];
  float* out = (float*)d_out;

  // ws layout
  _Float16* A16 = (_Float16*)d_ws;                    // NN*DD f16
  _Float16* B16 = A16 + (size_t)NN * DD;              // NN*DD f16
  _Float16* packW = B16 + (size_t)NN * DD;            // 5*16384 f16
  int* idx = (int*)(packW + 5 * 16384);               // 2*NE int
  int* hist = idx + 2 * (size_t)NE;                   // NB int
  int* cursor = hist + NB;                            // NB int
  int* sortedS = cursor + NB;                         // NE int
  int* sortedT = sortedS + NE;                        // NE int
  int* sortedE = sortedT + NE;                        // NE int

  zero_kernel<<<1, 256, 0, stream>>>(hist);
  prep_kernel<<<552, 256, 0, stream>>>(Wsrc, Wtgt, Wproj, Wmlp, eraw, idx,
                                       hist, packW);
  scan_kernel<<<1, 64, 0, stream>>>(hist, cursor);
  scatter_kernel<<<(NE + 1023) / 1024, 256, 0, stream>>>(idx, cursor, sortedS,
                                                         sortedT, sortedE);
  phase1_kernel<<<(NN + 63) / 64, 256, 0, stream>>>(X, packW, bproj, A16, B16);
  phase2_kernel<<<8 * BPC, 256, 0, stream>>>(A16, B16, sortedS, sortedT,
                                             sortedE, packW + 4 * 16384, bmlp,
                                             out);
}

// Round 9
// 193.709 us; speedup vs baseline: 1.0491x; 1.0491x over previous
//
#include <hip/hip_runtime.h>

#define NN 100000
#define NE 600000
#define DD 128

typedef _Float16 half4_t __attribute__((ext_vector_type(4)));
typedef _Float16 half8_t __attribute__((ext_vector_type(8)));
typedef float f32x4 __attribute__((ext_vector_type(4)));

// XOR-swizzle for [row][256B] f16 LDS tiles (G4). Byte address; flips bits
// 4-6 only, so 8B/16B alignment within a 16B slot is preserved.
__device__ __forceinline__ int swzb(int row, int byte) {
  return row * 256 + (byte ^ ((row & 7) << 4));
}

__device__ __forceinline__ half8_t relu_add(half8_t a, half8_t b) {
  half8_t r;
#pragma unroll
  for (int j = 0; j < 8; ++j) {
    const _Float16 s = a[j] + b[j];
    r[j] = s > (_Float16)0 ? s : (_Float16)0;
  }
  return r;
}

// ---------------------------------------------------------------------------
// Prep: pack 5 weight matrices (128x128 f32, row-major [k][n]) into f16
// fragment order (validated rounds 2-8):
//   packed[m][(nf*4+ks)*64 + l][j] = W[8*(l>>4)+32*ks+j][16*nf+(l&15)]
//   m: 0=W_src 1=W_tgt 2=W_proj[:128] 3=W_proj[128:] 4=W_mlp
// ---------------------------------------------------------------------------
__global__ void prep_kernel(const float* __restrict__ Wsrc,
                            const float* __restrict__ Wtgt,
                            const float* __restrict__ Wproj,
                            const float* __restrict__ Wmlp,
                            _Float16* __restrict__ packed) {
  const int t = (int)blockIdx.x * 256 + (int)threadIdx.x;
  if (t >= 5 * 2048) return;
  const int m = t >> 11;
  const int rem = t & 2047;
  const int nf = rem >> 8;
  const int ks = (rem >> 6) & 3;
  const int l = rem & 63;
  const float* W;
  if (m == 0) W = Wsrc;
  else if (m == 1) W = Wtgt;
  else if (m == 2) W = Wproj;
  else if (m == 3) W = Wproj + 128 * DD;
  else W = Wmlp;
  const int col = (l & 15) + 16 * nf;
  const int k0 = 8 * (l >> 4) + 32 * ks;
  half8_t v;
#pragma unroll
  for (int j = 0; j < 8; ++j) v[j] = (_Float16)W[(size_t)(k0 + j) * DD + col];
  *reinterpret_cast<half8_t*>(packed + (size_t)m * 16384 + (size_t)rem * 8) = v;
}

// ---------------------------------------------------------------------------
// Phase 1 (unchanged from R6/R7): per-node tables (f16 out).
//   A[n] = (sigmoid(x W_src) * x) @ W_proj[:128] + b_proj
//   B[n] = (sigmoid(x W_tgt) * x) @ W_proj[128:]
// 64 nodes/block, 4 waves; nf split across waves; W fragments in registers.
// ---------------------------------------------------------------------------
__global__ __launch_bounds__(256, 4)
void phase1_kernel(const float* __restrict__ Xg,
                   const _Float16* __restrict__ packW,
                   const float* __restrict__ bproj,
                   _Float16* __restrict__ Aout,
                   _Float16* __restrict__ Bout) {
  __shared__ _Float16 Xh[64 * DD];
  __shared__ _Float16 Th[64 * DD];
  const int tid = (int)threadIdx.x;
  const int row0 = (int)blockIdx.x * 64;
  const int rem = NN - row0;
  const int nvalid = rem < 64 ? rem : 64;

  // stage X tile -> f16 LDS (swizzled), coalesced 16B global reads
#pragma unroll
  for (int it = 0; it < 8; ++it) {
    const int i = tid + it * 256;
    const int r = i >> 5;
    const int c4 = i & 31;
    float4 v = make_float4(0.f, 0.f, 0.f, 0.f);
    if (r < nvalid)
      v = reinterpret_cast<const float4*>(Xg + (size_t)(row0 + r) * DD)[c4];
    half4_t h;
    h[0] = (_Float16)v.x; h[1] = (_Float16)v.y;
    h[2] = (_Float16)v.z; h[3] = (_Float16)v.w;
    *reinterpret_cast<half4_t*>(&Xh[swzb(r, c4 * 8) >> 1]) = h;
  }
  __syncthreads();

  const int l = tid & 63;
  const int w = tid >> 6;
  const int lr = l & 15;
  const int lg = l >> 4;

#pragma unroll 1
  for (int p = 0; p < 2; ++p) {
    // ---- W1 fragments for nf = 2w, 2w+1 -> registers (once per pass) ----
    const _Float16* __restrict__ wb1 = packW + (size_t)p * 16384 + l * 8;
    half8_t w1[2][4];
#pragma unroll
    for (int s = 0; s < 2; ++s)
#pragma unroll
      for (int ks = 0; ks < 4; ++ks)
        w1[s][ks] = *reinterpret_cast<const half8_t*>(
            wb1 + (size_t)(((2 * w + s) * 4 + ks)) * 512);

    // ---- GEMM1: S^T slice = W1^T X^T over all 4 node-groups ----
    f32x4 acc[4][2];
#pragma unroll
    for (int mf = 0; mf < 4; ++mf)
#pragma unroll
      for (int s = 0; s < 2; ++s) acc[mf][s] = (f32x4)0.f;
#pragma unroll
    for (int mf = 0; mf < 4; ++mf) {
      half8_t xf[4];
#pragma unroll
      for (int ks = 0; ks < 4; ++ks)
        xf[ks] = *reinterpret_cast<const half8_t*>(
            &Xh[swzb(mf * 16 + lr, lg * 16 + ks * 64) >> 1]);
#pragma unroll
      for (int ks = 0; ks < 4; ++ks)
#pragma unroll
        for (int s = 0; s < 2; ++s)
          acc[mf][s] = __builtin_amdgcn_mfma_f32_16x16x32_f16(
              w1[s][ks], xf[ks], acc[mf][s], 0, 0, 0);
    }

    // pass 1: all waves must finish GEMM2(p=0) reads of Th before overwrite
    if (p) __syncthreads();

    // ---- T = sigmoid(S) * x : lane holds S[mf*16+lr][(2w+s)*16+lg*4+j] ----
#pragma unroll
    for (int mf = 0; mf < 4; ++mf)
#pragma unroll
      for (int s = 0; s < 2; ++s) {
        const int c0 = (2 * w + s) * 16 + lg * 4;
        const int node = mf * 16 + lr;
        const half4_t xh =
            *reinterpret_cast<const half4_t*>(&Xh[swzb(node, c0 * 2) >> 1]);
        half4_t th;
#pragma unroll
        for (int j = 0; j < 4; ++j) {
          const float t = (float)xh[j] / (1.f + __expf(-acc[mf][s][j]));
          th[j] = (_Float16)t;
        }
        *reinterpret_cast<half4_t*>(&Th[swzb(node, c0 * 2) >> 1]) = th;
      }
    __syncthreads();

    // ---- W2 fragments -> registers; GEMM2: table^T slice = W2^T T^T ----
    const _Float16* __restrict__ wb2 = packW + (size_t)(2 + p) * 16384 + l * 8;
    half8_t w2[2][4];
#pragma unroll
    for (int s = 0; s < 2; ++s)
#pragma unroll
      for (int ks = 0; ks < 4; ++ks)
        w2[s][ks] = *reinterpret_cast<const half8_t*>(
            wb2 + (size_t)(((2 * w + s) * 4 + ks)) * 512);

    f32x4 acc2[4][2];
#pragma unroll
    for (int mf = 0; mf < 4; ++mf)
#pragma unroll
      for (int s = 0; s < 2; ++s) acc2[mf][s] = (f32x4)0.f;
#pragma unroll
    for (int mf = 0; mf < 4; ++mf) {
      half8_t tf[4];
#pragma unroll
      for (int ks = 0; ks < 4; ++ks)
        tf[ks] = *reinterpret_cast<const half8_t*>(
            &Th[swzb(mf * 16 + lr, lg * 16 + ks * 64) >> 1]);
#pragma unroll
      for (int ks = 0; ks < 4; ++ks)
#pragma unroll
        for (int s = 0; s < 2; ++s)
          acc2[mf][s] = __builtin_amdgcn_mfma_f32_16x16x32_f16(
              w2[s][ks], tf[ks], acc2[mf][s], 0, 0, 0);
    }

    // ---- store: lane owns table[node][(2w+s)*16+lg*4 .. +3] ----
    _Float16* __restrict__ dst = p ? Bout : Aout;
#pragma unroll
    for (int s = 0; s < 2; ++s) {
      const int c0 = (2 * w + s) * 16 + lg * 4;
      f32x4 bp = (f32x4)0.f;
      if (p == 0) bp = *reinterpret_cast<const f32x4*>(bproj + c0);
#pragma unroll
      for (int mf = 0; mf < 4; ++mf) {
        const int node = mf * 16 + lr;
        if (node < nvalid) {
          const f32x4 v = acc2[mf][s] + bp;
          half4_t h;
#pragma unroll
          for (int j = 0; j < 4; ++j) h[j] = (_Float16)v[j];
          *reinterpret_cast<half4_t*>(dst + (size_t)(row0 + node) * DD + c0) =
              h;
        }
      }
    }
  }
}

// ---------------------------------------------------------------------------
// Phase 2 (v5): out[e] = relu(A[src_e] + B[tgt_e]) @ W_mlp + b_mlp (f32 out)
// R7 structure, two changes:
//  * PLAIN stores (not nontemporal): NT bypasses L2, so the 16-row x 64B
//    interleaved store pattern hit the MC without write-combining; plain
//    stores stream through L2 like the 6.9 TB/s fillBuffer does.
//  * edge width (int64 vs int32) detected per-wave via ballot on the first
//    64 odd words of eraw (no idx workspace, no extra barrier).
// 64 edges/block, 4 waves; wave w owns edges [w*16, w*16+16).
// ---------------------------------------------------------------------------
__global__ __launch_bounds__(256, 5)
void phase2_kernel(const _Float16* __restrict__ At,
                   const _Float16* __restrict__ Bt,
                   const unsigned int* __restrict__ eraw,
                   const _Float16* __restrict__ Wpk,
                   const float* __restrict__ bmlp,
                   float* __restrict__ out) {
  __shared__ _Float16 Wl[16384];  // 32 KB: full packed W_mlp
  const int tid = (int)threadIdx.x;
  const int l = tid & 63;
  const int w = tid >> 6;
  const int lr = l & 15;
  const int lg = l >> 4;
  const int er = (int)blockIdx.x * 64 + w * 16 + lr;  // this lane's edge

  // per-wave width detect: int64 -> first 64 odd 32-bit words are all zero
  const int is64 = (__ballot(eraw[2 * l + 1] != 0u) == 0ull) ? 1 : 0;

  // dependent idx -> gather chain
  int ia, ib;
  if (is64) {
    ia = (int)eraw[2 * (size_t)er];
    ib = (int)eraw[2 * ((size_t)NE + er)];
  } else {
    ia = (int)eraw[er];
    ib = (int)eraw[(size_t)NE + er];
  }
  const _Float16* __restrict__ pa = At + (size_t)ia * DD + lg * 8;
  const _Float16* __restrict__ pb = Bt + (size_t)ib * DD + lg * 8;
  half8_t af[4], bf[4];
#pragma unroll
  for (int ks = 0; ks < 4; ++ks) {
    af[ks] = *reinterpret_cast<const half8_t*>(pa + ks * 32);
    bf[ks] = *reinterpret_cast<const half8_t*>(pb + ks * 32);
  }

  // stage W_mlp: 2048 x 16B chunks, contiguous & coalesced (overlaps gathers)
#pragma unroll
  for (int i = 0; i < 8; ++i) {
    const int c = tid + i * 256;
    reinterpret_cast<f32x4*>(Wl)[c] = reinterpret_cast<const f32x4*>(Wpk)[c];
  }

  f32x4 acc[8];
#pragma unroll
  for (int nf = 0; nf < 8; ++nf) acc[nf] = (f32x4)0.f;

  __syncthreads();  // drains vmcnt once: gathers + W loads all in flight

#pragma unroll
  for (int ks = 0; ks < 4; ++ks) {
    const half8_t r = relu_add(af[ks], bf[ks]);
#pragma unroll
    for (int nf = 0; nf < 8; ++nf) {
      const half8_t wf = *reinterpret_cast<const half8_t*>(
          &Wl[(size_t)(nf * 4 + ks) * 512 + l * 8]);
      acc[nf] =
          __builtin_amdgcn_mfma_f32_16x16x32_f16(wf, r, acc[nf], 0, 0, 0);
    }
  }

  // lane owns out[er][16nf+4lg .. +3] -> PLAIN float4 stores (via L2)
#pragma unroll
  for (int nf = 0; nf < 8; ++nf) {
    const int c0 = nf * 16 + lg * 4;
    const f32x4 bm = *reinterpret_cast<const f32x4*>(bmlp + c0);
    const f32x4 v = acc[nf] + bm;
    *reinterpret_cast<f32x4*>(out + (size_t)er * DD + c0) = v;
  }
}

// ---------------------------------------------------------------------------
extern "C" void kernel_launch(void* const* d_in, const int* in_sizes, int n_in,
                              void* d_out, int out_size, void* d_ws,
                              size_t ws_size, hipStream_t stream) {
  (void)in_sizes; (void)n_in; (void)out_size; (void)ws_size;

  const float* X = (const float*)d_in[0];
  const unsigned int* eraw = (const unsigned int*)d_in[1];
  const float* Wsrc = (const float*)d_in[2];
  const float* Wtgt = (const float*)d_in[3];
  const float* Wproj = (const float*)d_in[4];
  const float* bproj = (const float*)d_in[5];
  const float* Wmlp = (const float*)d_in[6];
  const float* bmlp = (const float*)d_in[7];
  float* out = (float*)d_out;

  // ws layout: A16[N*128] f16 | B16[N*128] f16 | packW[5*16384] f16
  _Float16* A16 = (_Float16*)d_ws;
  _Float16* B16 = A16 + (size_t)NN * DD;
  _Float16* packW = B16 + (size_t)NN * DD;

  prep_kernel<<<40, 256, 0, stream>>>(Wsrc, Wtgt, Wproj, Wmlp, packW);
  phase1_kernel<<<(NN + 63) / 64, 256, 0, stream>>>(X, packW, bproj, A16, B16);
  phase2_kernel<<<NE / 64, 256, 0, stream>>>(A16, B16, eraw,
                                             packW + 4 * 16384, bmlp, out);
}

// Round 10
// 144.129 us; speedup vs baseline: 1.4100x; 1.3440x over previous
//
#include <hip/hip_runtime.h>

#define NN 100000
#define NE 600000
#define DD 128

typedef _Float16 half4_t __attribute__((ext_vector_type(4)));
typedef _Float16 half8_t __attribute__((ext_vector_type(8)));
typedef float f32x4 __attribute__((ext_vector_type(4)));

// XOR-swizzle for [row][256B] f16 LDS tiles (G4). Byte address; flips bits
// 4-6 only, so 8B/16B alignment within a 16B slot is preserved.
__device__ __forceinline__ int swzb(int row, int byte) {
  return row * 256 + (byte ^ ((row & 7) << 4));
}

__device__ __forceinline__ half8_t relu_add(half8_t a, half8_t b) {
  half8_t r;
#pragma unroll
  for (int j = 0; j < 8; ++j) {
    const _Float16 s = a[j] + b[j];
    r[j] = s > (_Float16)0 ? s : (_Float16)0;
  }
  return r;
}

// ---------------------------------------------------------------------------
// Prep kernel (R7 baseline).
// Blocks [0,40): pack 5 weight matrices into f16 fragment order
//   packed[m][(nf*4+ks)*64 + l][j] = W[8*(l>>4)+32*ks+j][16*nf+(l&15)]
//   m: 0=W_src 1=W_tgt 2=W_proj[:128] 3=W_proj[128:] 4=W_mlp
// Blocks [40,552): decode edge_index into int32 idx[2*NE] (src then tgt);
// int64-vs-int32 width detected per block via ballot on first 64 odd words.
// ---------------------------------------------------------------------------
__global__ void prep_kernel(const float* __restrict__ Wsrc,
                            const float* __restrict__ Wtgt,
                            const float* __restrict__ Wproj,
                            const float* __restrict__ Wmlp,
                            const unsigned int* __restrict__ eraw,
                            int* __restrict__ idx,
                            _Float16* __restrict__ packed) {
  const int bid = (int)blockIdx.x;
  const int tid = (int)threadIdx.x;
  if (bid < 40) {
    const int t = bid * 256 + tid;
    if (t >= 5 * 2048) return;
    const int m = t >> 11;
    const int rem = t & 2047;
    const int nf = rem >> 8;
    const int ks = (rem >> 6) & 3;
    const int l = rem & 63;
    const float* W;
    if (m == 0) W = Wsrc;
    else if (m == 1) W = Wtgt;
    else if (m == 2) W = Wproj;
    else if (m == 3) W = Wproj + 128 * DD;
    else W = Wmlp;
    const int col = (l & 15) + 16 * nf;
    const int k0 = 8 * (l >> 4) + 32 * ks;
    half8_t v;
#pragma unroll
    for (int j = 0; j < 8; ++j)
      v[j] = (_Float16)W[(size_t)(k0 + j) * DD + col];
    *reinterpret_cast<half8_t*>(packed + (size_t)m * 16384 +
                                (size_t)rem * 8) = v;
  } else {
    __shared__ int s_is64;
    if (tid < 64) {
      const unsigned long long b = __ballot(eraw[2 * tid + 1] != 0u);
      if (tid == 0) s_is64 = (b == 0ull) ? 1 : 0;
    }
    __syncthreads();
    const int is64 = s_is64;
    const size_t stride = (size_t)512 * 256;
    for (size_t i = (size_t)(bid - 40) * 256 + tid; i < 2 * (size_t)NE;
         i += stride)
      idx[i] = (int)(is64 ? eraw[2 * i] : eraw[i]);
  }
}

// ---------------------------------------------------------------------------
// Phase 1 (unchanged from R6/R7): per-node tables (f16 out).
//   A[n] = (sigmoid(x W_src) * x) @ W_proj[:128] + b_proj
//   B[n] = (sigmoid(x W_tgt) * x) @ W_proj[128:]
// 64 nodes/block, 4 waves; nf split across waves; W fragments in registers.
// ---------------------------------------------------------------------------
__global__ __launch_bounds__(256, 4)
void phase1_kernel(const float* __restrict__ Xg,
                   const _Float16* __restrict__ packW,
                   const float* __restrict__ bproj,
                   _Float16* __restrict__ Aout,
                   _Float16* __restrict__ Bout) {
  __shared__ _Float16 Xh[64 * DD];
  __shared__ _Float16 Th[64 * DD];
  const int tid = (int)threadIdx.x;
  const int row0 = (int)blockIdx.x * 64;
  const int rem = NN - row0;
  const int nvalid = rem < 64 ? rem : 64;

#pragma unroll
  for (int it = 0; it < 8; ++it) {
    const int i = tid + it * 256;
    const int r = i >> 5;
    const int c4 = i & 31;
    float4 v = make_float4(0.f, 0.f, 0.f, 0.f);
    if (r < nvalid)
      v = reinterpret_cast<const float4*>(Xg + (size_t)(row0 + r) * DD)[c4];
    half4_t h;
    h[0] = (_Float16)v.x; h[1] = (_Float16)v.y;
    h[2] = (_Float16)v.z; h[3] = (_Float16)v.w;
    *reinterpret_cast<half4_t*>(&Xh[swzb(r, c4 * 8) >> 1]) = h;
  }
  __syncthreads();

  const int l = tid & 63;
  const int w = tid >> 6;
  const int lr = l & 15;
  const int lg = l >> 4;

#pragma unroll 1
  for (int p = 0; p < 2; ++p) {
    const _Float16* __restrict__ wb1 = packW + (size_t)p * 16384 + l * 8;
    half8_t w1[2][4];
#pragma unroll
    for (int s = 0; s < 2; ++s)
#pragma unroll
      for (int ks = 0; ks < 4; ++ks)
        w1[s][ks] = *reinterpret_cast<const half8_t*>(
            wb1 + (size_t)(((2 * w + s) * 4 + ks)) * 512);

    f32x4 acc[4][2];
#pragma unroll
    for (int mf = 0; mf < 4; ++mf)
#pragma unroll
      for (int s = 0; s < 2; ++s) acc[mf][s] = (f32x4)0.f;
#pragma unroll
    for (int mf = 0; mf < 4; ++mf) {
      half8_t xf[4];
#pragma unroll
      for (int ks = 0; ks < 4; ++ks)
        xf[ks] = *reinterpret_cast<const half8_t*>(
            &Xh[swzb(mf * 16 + lr, lg * 16 + ks * 64) >> 1]);
#pragma unroll
      for (int ks = 0; ks < 4; ++ks)
#pragma unroll
        for (int s = 0; s < 2; ++s)
          acc[mf][s] = __builtin_amdgcn_mfma_f32_16x16x32_f16(
              w1[s][ks], xf[ks], acc[mf][s], 0, 0, 0);
    }

    if (p) __syncthreads();

#pragma unroll
    for (int mf = 0; mf < 4; ++mf)
#pragma unroll
      for (int s = 0; s < 2; ++s) {
        const int c0 = (2 * w + s) * 16 + lg * 4;
        const int node = mf * 16 + lr;
        const half4_t xh =
            *reinterpret_cast<const half4_t*>(&Xh[swzb(node, c0 * 2) >> 1]);
        half4_t th;
#pragma unroll
        for (int j = 0; j < 4; ++j) {
          const float t = (float)xh[j] / (1.f + __expf(-acc[mf][s][j]));
          th[j] = (_Float16)t;
        }
        *reinterpret_cast<half4_t*>(&Th[swzb(node, c0 * 2) >> 1]) = th;
      }
    __syncthreads();

    const _Float16* __restrict__ wb2 = packW + (size_t)(2 + p) * 16384 + l * 8;
    half8_t w2[2][4];
#pragma unroll
    for (int s = 0; s < 2; ++s)
#pragma unroll
      for (int ks = 0; ks < 4; ++ks)
        w2[s][ks] = *reinterpret_cast<const half8_t*>(
            wb2 + (size_t)(((2 * w + s) * 4 + ks)) * 512);

    f32x4 acc2[4][2];
#pragma unroll
    for (int mf = 0; mf < 4; ++mf)
#pragma unroll
      for (int s = 0; s < 2; ++s) acc2[mf][s] = (f32x4)0.f;
#pragma unroll
    for (int mf = 0; mf < 4; ++mf) {
      half8_t tf[4];
#pragma unroll
      for (int ks = 0; ks < 4; ++ks)
        tf[ks] = *reinterpret_cast<const half8_t*>(
            &Th[swzb(mf * 16 + lr, lg * 16 + ks * 64) >> 1]);
#pragma unroll
      for (int ks = 0; ks < 4; ++ks)
#pragma unroll
        for (int s = 0; s < 2; ++s)
          acc2[mf][s] = __builtin_amdgcn_mfma_f32_16x16x32_f16(
              w2[s][ks], tf[ks], acc2[mf][s], 0, 0, 0);
    }

    _Float16* __restrict__ dst = p ? Bout : Aout;
#pragma unroll
    for (int s = 0; s < 2; ++s) {
      const int c0 = (2 * w + s) * 16 + lg * 4;
      f32x4 bp = (f32x4)0.f;
      if (p == 0) bp = *reinterpret_cast<const f32x4*>(bproj + c0);
#pragma unroll
      for (int mf = 0; mf < 4; ++mf) {
        const int node = mf * 16 + lr;
        if (node < nvalid) {
          const f32x4 v = acc2[mf][s] + bp;
          half4_t h;
#pragma unroll
          for (int j = 0; j < 4; ++j) h[j] = (_Float16)v[j];
          *reinterpret_cast<half4_t*>(dst + (size_t)(row0 + node) * DD + c0) =
              h;
        }
      }
    }
  }
}

// ---------------------------------------------------------------------------
// Phase 2 (v6): out[e] = relu(A[src_e] + B[tgt_e]) @ W_mlp + b_mlp (f32 out)
// R7 structure (idx pre-decoded, all gathers upfront, W_mlp in 32 KB LDS,
// NT stores) with ONE change: the epilogue re-stages each wave's output tile
// (16 consecutive edges x 512 B = contiguous 8 KB of `out`) through the
// now-dead W_mlp LDS buffer, then streams it with 8 fully-SEQUENTIAL 1 KB NT
// store instructions. R9 showed the store path is the sensitive resource;
// this replaces 64B-scattered NT writes with large ordered bursts at the MC.
// 64 edges/block, 4 waves; wave w owns edges [w*16, w*16+16).
// ---------------------------------------------------------------------------
__global__ __launch_bounds__(256, 5)
void phase2_kernel(const _Float16* __restrict__ At,
                   const _Float16* __restrict__ Bt,
                   const int* __restrict__ idx,
                   const _Float16* __restrict__ Wpk,
                   const float* __restrict__ bmlp,
                   float* __restrict__ out) {
  __shared__ _Float16 Wl[16384];  // 32 KB: packed W_mlp, later output tiles
  const int tid = (int)threadIdx.x;
  const int l = tid & 63;
  const int w = tid >> 6;
  const int lr = l & 15;
  const int lg = l >> 4;
  const int e0 = (int)blockIdx.x * 64;           // block's first edge
  const int er = e0 + w * 16 + lr;               // this lane's edge

  // dependent idx -> gather chain first
  const int ia = idx[er];
  const int ib = idx[(size_t)NE + er];
  const _Float16* __restrict__ pa = At + (size_t)ia * DD + lg * 8;
  const _Float16* __restrict__ pb = Bt + (size_t)ib * DD + lg * 8;
  half8_t af[4], bf[4];
#pragma unroll
  for (int ks = 0; ks < 4; ++ks) {
    af[ks] = *reinterpret_cast<const half8_t*>(pa + ks * 32);
    bf[ks] = *reinterpret_cast<const half8_t*>(pb + ks * 32);
  }

  // stage W_mlp (overlaps the gathers in the same vmcnt window)
#pragma unroll
  for (int i = 0; i < 8; ++i) {
    const int c = tid + i * 256;
    reinterpret_cast<f32x4*>(Wl)[c] = reinterpret_cast<const f32x4*>(Wpk)[c];
  }

  f32x4 acc[8];
#pragma unroll
  for (int nf = 0; nf < 8; ++nf) acc[nf] = (f32x4)0.f;

  __syncthreads();  // drains vmcnt once: gathers + W loads all in flight

#pragma unroll
  for (int ks = 0; ks < 4; ++ks) {
    const half8_t r = relu_add(af[ks], bf[ks]);
#pragma unroll
    for (int nf = 0; nf < 8; ++nf) {
      const half8_t wf = *reinterpret_cast<const half8_t*>(
          &Wl[(size_t)(nf * 4 + ks) * 512 + l * 8]);
      acc[nf] =
          __builtin_amdgcn_mfma_f32_16x16x32_f16(wf, r, acc[nf], 0, 0, 0);
    }
  }

  // bias add in registers
#pragma unroll
  for (int nf = 0; nf < 8; ++nf) {
    const int c0 = nf * 16 + lg * 4;
    acc[nf] = acc[nf] + *reinterpret_cast<const f32x4*>(bmlp + c0);
  }

  __syncthreads();  // all waves done reading W_mlp fragments from Wl

  // re-stage this wave's 16x512B output tile in LDS (bank-XOR on row bits),
  // then stream the contiguous 8 KB region with 8 sequential 1 KB NT insts.
  float* __restrict__ tile = reinterpret_cast<float*>(Wl) + w * 2048;
#pragma unroll
  for (int nf = 0; nf < 8; ++nf) {
    const int o = nf * 64 + lg * 16;  // byte offset within the 512B row
    *reinterpret_cast<f32x4*>(
        reinterpret_cast<char*>(tile) + lr * 512 + (o ^ ((lr & 7) << 4))) =
        acc[nf];
  }
  // wave-private tile: compiler-inserted lgkmcnt orders write->read
  float* __restrict__ gbase = out + (size_t)(e0 + w * 16) * DD;
#pragma unroll
  for (int i = 0; i < 8; ++i) {
    const int o = i * 1024 + l * 16;  // byte offset within the 8 KB tile
    const int row = o >> 9;
    const int bi = o & 511;
    const f32x4 v = *reinterpret_cast<const f32x4*>(
        reinterpret_cast<const char*>(tile) + row * 512 +
        (bi ^ ((row & 7) << 4)));
    __builtin_nontemporal_store(
        v, reinterpret_cast<f32x4*>(reinterpret_cast<char*>(gbase) + o));
  }
}

// ---------------------------------------------------------------------------
extern "C" void kernel_launch(void* const* d_in, const int* in_sizes, int n_in,
                              void* d_out, int out_size, void* d_ws,
                              size_t ws_size, hipStream_t stream) {
  (void)in_sizes; (void)n_in; (void)out_size; (void)ws_size;

  const float* X = (const float*)d_in[0];
  const unsigned int* eraw = (const unsigned int*)d_in[1];
  const float* Wsrc = (const float*)d_in[2];
  const float* Wtgt = (const float*)d_in[3];
  const float* Wproj = (const float*)d_in[4];
  const float* bproj = (const float*)d_in[5];
  const float* Wmlp = (const float*)d_in[6];
  const float* bmlp = (const float*)d_in[7];
  float* out = (float*)d_out;

  // ws layout: A16[N*128] f16 | B16[N*128] f16 | packW[5*16384] f16 |
  //            idx[2*NE] int32
  _Float16* A16 = (_Float16*)d_ws;
  _Float16* B16 = A16 + (size_t)NN * DD;
  _Float16* packW = B16 + (size_t)NN * DD;
  int* idx = (int*)(packW + 5 * 16384);

  prep_kernel<<<552, 256, 0, stream>>>(Wsrc, Wtgt, Wproj, Wmlp, eraw, idx,
                                       packW);
  phase1_kernel<<<(NN + 63) / 64, 256, 0, stream>>>(X, packW, bproj, A16, B16);
  phase2_kernel<<<NE / 64, 256, 0, stream>>>(A16, B16, idx,
                                             packW + 4 * 16384, bmlp, out);
}